// Round 12
// baseline (1156.488 us; speedup 1.0000x reference)
//
#include <hip/hip_runtime.h>

typedef float f32x4  __attribute__((ext_vector_type(4)));
typedef float f32x16 __attribute__((ext_vector_type(16)));
typedef int   i32x4  __attribute__((ext_vector_type(4)));
typedef int   i32x8  __attribute__((ext_vector_type(8)));

#define T_DIM 8192
#define H_DIM 4096
#define SC1 0x7f7f7f7f   // e8m0 scale = 127 -> 2^0 = 1.0 in all 4 bytes

__device__ __forceinline__ unsigned int pack_fp8x4(float a, float b, float c, float d) {
    int v = __builtin_amdgcn_cvt_pk_fp8_f32(a, b, 0, false);
    v = __builtin_amdgcn_cvt_pk_fp8_f32(c, d, v, true);
    return (unsigned int)v;
}

// ---------------------------------------------------------------------------
// qx (A): PLAIN row-major [row][k]; reg-staged into LDS with XOR slot swizzle
//   slot' = slot ^ ((row>>1)&3) applied on the GLOBAL source address (LDS
//   image linear); ds_read applies the same XOR -> bank-balanced b128.
// wqT (B): FRAG-MAJOR: addr = ((((l*16+bn)*64+kt)*4+wc)*2+n2)*2048
//   + lane*32 + byte, lane = ((k>>5)&1)*32 + (n&31).  A wave's B-frag load is
//   ONE coalesced 2KB read, consumed direct from global (L1/L2).
// GEMM: acc initialized from C/alpha (prologue, overlaps warmup); epilogue is
//   a pure store C = acc*alpha.  3-buffer LDS: ds_write A(t+2), read A(t+1),
//   compute t; one barrier + one lgkm(0) per tile at iteration END.
// ---------------------------------------------------------------------------

// w[l][k][n] f32  ->  wqT[l] frag-major fp8(e4m3)
__global__ __launch_bounds__(256) void wquant_kernel(
    const float* __restrict__ w, unsigned char* __restrict__ wqT)
{
    const int l  = blockIdx.z;
    const int n0 = blockIdx.x * 64;
    const int k0 = blockIdx.y * 64;
    const int tid = threadIdx.x;
    __shared__ unsigned char tile[64][68];   // [k][n]
    const float* wl = w + (size_t)l * H_DIM * H_DIM;
#pragma unroll
    for (int p = 0; p < 4; ++p) {
        int r = p * 16 + (tid >> 4);         // k within tile
        int c = (tid & 15) * 4;              // n within tile
        f32x4 v = *(const f32x4*)(wl + (size_t)(k0 + r) * H_DIM + n0 + c);
        *(unsigned int*)&tile[r][c] = pack_fp8x4(v[0], v[1], v[2], v[3]);
    }
    __syncthreads();
    const int nl = tid >> 2;                 // n within tile
    const int g  = tid & 3;                  // 16B k-chunk within 64
    unsigned int words[4];
#pragma unroll
    for (int wi = 0; wi < 4; ++wi) {
        unsigned int a = 0;
#pragma unroll
        for (int b = 0; b < 4; ++b)
            a |= (unsigned int)tile[g * 16 + wi * 4 + b][nl] << (8 * b);
        words[wi] = a;
    }
    const int bn = n0 >> 8, wc = (n0 >> 6) & 3, kt = k0 >> 6;
    const int n2 = nl >> 5;
    const int lane = (g >> 1) * 32 + (nl & 31);
    const int byte0 = (g & 1) * 16;
    const size_t off = ((((size_t)l * 16 + bn) * 64 + kt) * 4 + wc) * 2 + n2;
    unsigned char* op = wqT + off * 2048 + lane * 32 + byte0;
    uint4 ov; ov.x = words[0]; ov.y = words[1]; ov.z = words[2]; ov.w = words[3];
    *(uint4*)op = ov;
}

// ---------------- row-wise RMSNorm (+relu) (+quant) ----------------
// MODE 0: x = relu(in); resid_out = x; qx = fp8 (plain layout)
// MODE 1: x = in;                      qx = fp8 (plain layout)
// MODE 2: x = in;                      out = f32 rms(x)*g
template <int MODE>
__global__ __launch_bounds__(256) void row_kernel(
    const float* __restrict__ in,
    float* __restrict__ resid_out,
    void* __restrict__ out,
    const float* __restrict__ g,
    const float* __restrict__ scale_p)
{
    const int row = blockIdx.x;
    const int tid = threadIdx.x;
    const float* rin = in + (size_t)row * H_DIM;
    float x[16];
    float ss = 0.0f;
#pragma unroll
    for (int j = 0; j < 4; ++j) {
        const int base = (j * 256 + tid) * 4;
        f32x4 v = *(const f32x4*)(rin + base);
        f32x4 rv;
#pragma unroll
        for (int i = 0; i < 4; ++i) {
            float t = v[i];
            if (MODE == 0) t = fmaxf(t, 0.0f);
            x[j * 4 + i] = t;
            rv[i] = t;
            ss += t * t;
        }
        if (MODE == 0)
            *(f32x4*)(resid_out + (size_t)row * H_DIM + base) = rv;
    }
#pragma unroll
    for (int off = 32; off > 0; off >>= 1)
        ss += __shfl_down(ss, off, 64);
    __shared__ float red[4];
    if ((tid & 63) == 0) red[tid >> 6] = ss;
    __syncthreads();
    const float var  = (red[0] + red[1] + red[2] + red[3]) * (1.0f / (float)H_DIM);
    const float rinv = 1.0f / sqrtf(var + 1e-6f);

    if (MODE == 2) {
        float* ro = (float*)out + (size_t)row * H_DIM;
#pragma unroll
        for (int j = 0; j < 4; ++j) {
            const int base = (j * 256 + tid) * 4;
            f32x4 gv = *(const f32x4*)(g + base);
            f32x4 ov;
#pragma unroll
            for (int i = 0; i < 4; ++i) ov[i] = (x[j * 4 + i] * rinv) * gv[i];
            *(f32x4*)(ro + base) = ov;
        }
    } else {
        const float s = scale_p[0];
        unsigned int* qo = (unsigned int*)out + (size_t)row * (H_DIM / 4);
#pragma unroll
        for (int j = 0; j < 4; ++j) {
            const int base = (j * 256 + tid) * 4;
            f32x4 gv = *(const f32x4*)(g + base);
            float q[4];
#pragma unroll
            for (int i = 0; i < 4; ++i) {
                float y = (x[j * 4 + i] * rinv) * gv[i];
                y = y / s;
                q[i] = fminf(fmaxf(y, -448.0f), 448.0f);
            }
            qo[j * 256 + tid] = pack_fp8x4(q[0], q[1], q[2], q[3]);
        }
    }
}

// ---- MX-fp8 GEMM, 256x256 tile, BK=64, A 3-buf LDS, B direct frag-major ----
#define BUF0 0
#define BUF1 16384
#define BUF2 32768

#define MM2(m, P) do {                                                          \
    acc[m][0] = __builtin_amdgcn_mfma_scale_f32_32x32x64_f8f6f4(                \
        fa[m], b##P##0, acc[m][0], 0, 0, 0, SC1, 0, SC1);                       \
    acc[m][1] = __builtin_amdgcn_mfma_scale_f32_32x32x64_f8f6f4(                \
        fa[m], b##P##1, acc[m][1], 0, 0, 0, SC1, 0, SC1);                       \
} while (0)

#define RDA(ORQ, m) do {                                                        \
    *(i32x4*)&fa[m]         = *(const i32x4*)(lds + (ORQ) + wrA + (m) * 2048 + fo0); \
    *(((i32x4*)&fa[m]) + 1) = *(const i32x4*)(lds + (ORQ) + wrA + (m) * 2048 + fo1); \
} while (0)

// iter t: gload A(t+3)->rLD, gload B(t+1)->bFN, ds_write A(t+2)=rWR -> BUFW,
// MFMA(t) with bFC interleaved with ds_read of A(t+1) frags from BUFR,
// then lgkm(0)+barrier (write->read handoff for BUFW at iter t+1).
#define ITER(WR, LD, FC, FN, BUFW, BUFR) do {                                   \
    r##LD##a = *(const i32x4*)(gAlo + ka);                                      \
    r##LD##b = *(const i32x4*)(gAhi + ka); ka += 64;                            \
    b##FN##0 = *(const i32x8*)(gB0 + kb);                                       \
    b##FN##1 = *(const i32x8*)(gB0 + kb + 2048); kb += 16384;                   \
    *(i32x4*)(lds + (BUFW) + tid16)        = r##WR##a;                          \
    *(i32x4*)(lds + (BUFW) + 8192 + tid16) = r##WR##b;                          \
    __builtin_amdgcn_s_setprio(1); MM2(0, FC); __builtin_amdgcn_s_setprio(0);   \
    RDA(BUFR, 0);                                                               \
    __builtin_amdgcn_s_setprio(1); MM2(1, FC); __builtin_amdgcn_s_setprio(0);   \
    RDA(BUFR, 1);                                                               \
    __builtin_amdgcn_s_setprio(1); MM2(2, FC); __builtin_amdgcn_s_setprio(0);   \
    RDA(BUFR, 2);                                                               \
    __builtin_amdgcn_s_setprio(1); MM2(3, FC); __builtin_amdgcn_s_setprio(0);   \
    RDA(BUFR, 3);                                                               \
    asm volatile("s_waitcnt lgkmcnt(0)" ::: "memory");                          \
    __builtin_amdgcn_s_barrier();                                               \
} while (0)

__global__ __launch_bounds__(512, 2) void gemm_fp8_kernel(
    const unsigned char* __restrict__ A,   // qx, plain row-major
    const unsigned char* __restrict__ B,   // wqT layer, frag-major
    float* __restrict__ C,
    const float* __restrict__ s_in,
    const float* __restrict__ s_w)
{
    __shared__ unsigned char lds[49152];   // 3 bufs x 16K (A only)

    const float alpha  = s_in[0] * s_w[0];
    const float ralpha = 1.0f / alpha;

    // XCD-bijective swizzle (512 blocks = 64/XCD) + 8x8 supertile per XCD
    const int b = blockIdx.x;
    const int local = b >> 3, chunk = b & 7;         // chunk = XCD id
    const int bm = (chunk & 3) * 8 + (local & 7);    // M/256 = 32
    const int bn = (chunk >> 2) * 8 + (local >> 3);  // N/256 = 16

    const int tid  = threadIdx.x;
    const int wave = tid >> 6;
    const int lane = tid & 63;
    const int wr   = wave >> 2;   // 2 M-waves
    const int wc   = wave & 3;    // 4 N-waves

    // A frag ds_read: row=(lane&31), slot=(lane>>5)*2+h, stored^((row>>1)&3)
    const int sw  = (lane >> 1) & 3;
    const int fo0 = (lane & 31) * 64 + ((((lane >> 5) * 2) + 0 ^ sw)) * 16;
    const int fo1 = (lane & 31) * 64 + ((((lane >> 5) * 2) + 1 ^ sw)) * 16;
    const int wrA = wr * 8192;            // A region: 128 rows per wr

    // A staging: thread tid covers LDS [row=tid>>2][slot=tid&3]; global XOR'd
    const int voff = (tid >> 2) * H_DIM + ((tid & 3) ^ ((tid >> 3) & 3)) * 16;
    const unsigned char* gAlo = A + (size_t)bm * 256 * H_DIM + voff;
    const unsigned char* gAhi = gAlo + (size_t)128 * H_DIM;
    const int tid16 = tid * 16;

    // B frag-major: base for (bn, kt=0, wc, n2=0) + lane*32; coalesced 2KB/wave
    const unsigned char* gB0 =
        B + ((((size_t)bn * 64) * 4 + wc) * 2) * 2048 + lane * 32;

    // output coords (also used for the C prologue read)
    const int lrow0 = bm * 256 + wr * 128 + 4 * (lane >> 5);
    const int lcol0 = bn * 256 + wc * 64 + (lane & 31);

    // acc = C/alpha : moves the residual read into the prologue (overlaps
    // warmup + early tiles); epilogue becomes a pure store.
    f32x16 acc[4][2];
#pragma unroll
    for (int m = 0; m < 4; ++m)
#pragma unroll
        for (int n = 0; n < 2; ++n)
#pragma unroll
            for (int e = 0; e < 16; ++e) {
                const int row = lrow0 + m * 32 + (e & 3) + 8 * (e >> 2);
                acc[m][n][e] =
                    C[(size_t)row * H_DIM + lcol0 + n * 32] * ralpha;
            }

    i32x8 fa[4];
    i32x4 rXa, rXb, rYa, rYb;
    i32x8 bX0, bX1, bY0, bY1;

    // prologue: A(0)->buf0, A(1)->buf1, A(2)->X regs, B(0)->X; frags tile0
    rXa = *(const i32x4*)(gAlo);
    rXb = *(const i32x4*)(gAhi);
    rYa = *(const i32x4*)(gAlo + 64);
    rYb = *(const i32x4*)(gAhi + 64);
    *(i32x4*)(lds + BUF0 + tid16)        = rXa;
    *(i32x4*)(lds + BUF0 + 8192 + tid16) = rXb;
    *(i32x4*)(lds + BUF1 + tid16)        = rYa;
    *(i32x4*)(lds + BUF1 + 8192 + tid16) = rYb;
    rXa = *(const i32x4*)(gAlo + 128);   // A(2) -> X set
    rXb = *(const i32x4*)(gAhi + 128);
    bX0 = *(const i32x8*)(gB0);          // B(0) -> X set
    bX1 = *(const i32x8*)(gB0 + 2048);
    asm volatile("s_waitcnt lgkmcnt(0)" ::: "memory");
    __builtin_amdgcn_s_barrier();
    RDA(BUF0, 0); RDA(BUF0, 1); RDA(BUF0, 2); RDA(BUF0, 3);
    int ka = 192;     // next A gload: tile 3
    int kb = 16384;   // next B gload: tile 1

    // t = 0..59 (10 x 6-unrolled): buf pattern period 3, reg parity period 2
#pragma unroll 1
    for (int it = 0; it < 10; ++it) {
        ITER(X, Y, X, Y, BUF2, BUF1);   // t%6==0
        ITER(Y, X, Y, X, BUF0, BUF2);   // t%6==1
        ITER(X, Y, X, Y, BUF1, BUF0);   // t%6==2
        ITER(Y, X, Y, X, BUF2, BUF1);   // t%6==3
        ITER(X, Y, X, Y, BUF0, BUF2);   // t%6==4
        ITER(Y, X, Y, X, BUF1, BUF0);   // t%6==5
    }
    // t = 60 (full iter; loads A(63), writes A(62), B(61))
    ITER(X, Y, X, Y, BUF2, BUF1);
    // t = 61: no A gload; write A(63)->buf0; B(62)->X; frags A(62) from buf2
    bX0 = *(const i32x8*)(gB0 + kb);
    bX1 = *(const i32x8*)(gB0 + kb + 2048); kb += 16384;
    *(i32x4*)(lds + BUF0 + tid16)        = rYa;
    *(i32x4*)(lds + BUF0 + 8192 + tid16) = rYb;
    __builtin_amdgcn_s_setprio(1); MM2(0, Y); __builtin_amdgcn_s_setprio(0);
    RDA(BUF2, 0);
    __builtin_amdgcn_s_setprio(1); MM2(1, Y); __builtin_amdgcn_s_setprio(0);
    RDA(BUF2, 1);
    __builtin_amdgcn_s_setprio(1); MM2(2, Y); __builtin_amdgcn_s_setprio(0);
    RDA(BUF2, 2);
    __builtin_amdgcn_s_setprio(1); MM2(3, Y); __builtin_amdgcn_s_setprio(0);
    RDA(BUF2, 3);
    asm volatile("s_waitcnt lgkmcnt(0)" ::: "memory");
    __builtin_amdgcn_s_barrier();
    // t = 62: B(63)->Y; frags A(63) from buf0; no write, no barrier after
    bY0 = *(const i32x8*)(gB0 + kb);
    bY1 = *(const i32x8*)(gB0 + kb + 2048);
    __builtin_amdgcn_s_setprio(1); MM2(0, X); __builtin_amdgcn_s_setprio(0);
    RDA(BUF0, 0);
    __builtin_amdgcn_s_setprio(1); MM2(1, X); __builtin_amdgcn_s_setprio(0);
    RDA(BUF0, 1);
    __builtin_amdgcn_s_setprio(1); MM2(2, X); __builtin_amdgcn_s_setprio(0);
    RDA(BUF0, 2);
    __builtin_amdgcn_s_setprio(1); MM2(3, X); __builtin_amdgcn_s_setprio(0);
    RDA(BUF0, 3);
    // t = 63
    MM2(0, Y); MM2(1, Y); MM2(2, Y); MM2(3, Y);

    // epilogue: pure store C = acc*alpha
#pragma unroll
    for (int m = 0; m < 4; ++m) {
#pragma unroll
        for (int n = 0; n < 2; ++n) {
#pragma unroll
            for (int e = 0; e < 16; ++e) {
                const int row = lrow0 + m * 32 + (e & 3) + 8 * (e >> 2);
                C[(size_t)row * H_DIM + lcol0 + n * 32] = acc[m][n][e] * alpha;
            }
        }
    }
}

extern "C" void kernel_launch(void* const* d_in, const int* in_sizes, int n_in,
                              void* d_out, int out_size, void* d_ws, size_t ws_size,
                              hipStream_t stream) {
    const float* h   = (const float*)d_in[0];   // [8192,4096]
    const float* nw  = (const float*)d_in[1];   // [4,4096]
    const float* w   = (const float*)d_in[2];   // [3,4096,4096]
    const float* wsc = (const float*)d_in[3];   // [3]
    const float* sc  = (const float*)d_in[4];   // [3]
    float* out = (float*)d_out;

    unsigned char* wqT = (unsigned char*)d_ws;                       // 3*16M fp8
    unsigned char* qx  = wqT + (size_t)3 * H_DIM * H_DIM;            // 33.5M fp8
    float* resid = (float*)(qx + (size_t)T_DIM * H_DIM);             // 134M f32

    const size_t WSTRIDE = (size_t)H_DIM * H_DIM;

    wquant_kernel<<<dim3(64, 64, 3), 256, 0, stream>>>(w, wqT);

    row_kernel<0><<<T_DIM, 256, 0, stream>>>(h, resid, qx, nw + 0 * H_DIM, sc + 0);
    gemm_fp8_kernel<<<512, 512, 0, stream>>>(qx, wqT + 0 * WSTRIDE, resid, sc + 0, wsc + 0);

    row_kernel<1><<<T_DIM, 256, 0, stream>>>(resid, nullptr, qx, nw + 1 * H_DIM, sc + 1);
    gemm_fp8_kernel<<<512, 512, 0, stream>>>(qx, wqT + 1 * WSTRIDE, resid, sc + 1, wsc + 1);

    row_kernel<1><<<T_DIM, 256, 0, stream>>>(resid, nullptr, qx, nw + 2 * H_DIM, sc + 2);
    gemm_fp8_kernel<<<512, 512, 0, stream>>>(qx, wqT + 2 * WSTRIDE, resid, sc + 2, wsc + 2);

    row_kernel<2><<<T_DIM, 256, 0, stream>>>(resid, nullptr, out, nw + 3 * H_DIM, nullptr);
}

// Round 13
// 754.856 us; speedup vs baseline: 1.5321x; 1.5321x over previous
//
#include <hip/hip_runtime.h>

typedef float f32x4  __attribute__((ext_vector_type(4)));
typedef float f32x16 __attribute__((ext_vector_type(16)));
typedef int   i32x4  __attribute__((ext_vector_type(4)));
typedef int   i32x8  __attribute__((ext_vector_type(8)));

#define T_DIM 8192
#define H_DIM 4096
#define SC1 0x7f7f7f7f   // e8m0 scale = 127 -> 2^0 = 1.0 in all 4 bytes

__device__ __forceinline__ unsigned int pack_fp8x4(float a, float b, float c, float d) {
    int v = __builtin_amdgcn_cvt_pk_fp8_f32(a, b, 0, false);
    v = __builtin_amdgcn_cvt_pk_fp8_f32(c, d, v, true);
    return (unsigned int)v;
}

// ---------------------------------------------------------------------------
// qx (A): PLAIN row-major [row][k]; staged via global_load_lds with XOR slot
//   swizzle slot' = slot ^ ((row>>1)&3) applied on the GLOBAL source address
//   (LDS image linear); ds_read applies the same XOR -> bank-balanced b128.
// wqT (B): FRAG-MAJOR: addr = ((((l*16+bn)*64+kt)*4+wc)*2+n2)*2048
//   + lane*32 + byte, lane = ((k>>5)&1)*32 + (n&31).  A wave's B-frag load is
//   ONE coalesced 2KB read, consumed direct from global (L1/L2).
// GEMM: 2 K-tiles per sync period (one VM8 + one barrier per 2 tiles);
//   A 6-deep LDS (96KB), staged 2 periods ahead; B 2-period double-buffered
//   in registers.  Counted vmcnt only (never 0 in the main loop).
// ---------------------------------------------------------------------------

// w[l][k][n] f32  ->  wqT[l] frag-major fp8(e4m3)
__global__ __launch_bounds__(256) void wquant_kernel(
    const float* __restrict__ w, unsigned char* __restrict__ wqT)
{
    const int l  = blockIdx.z;
    const int n0 = blockIdx.x * 64;
    const int k0 = blockIdx.y * 64;
    const int tid = threadIdx.x;
    __shared__ unsigned char tile[64][68];   // [k][n]
    const float* wl = w + (size_t)l * H_DIM * H_DIM;
#pragma unroll
    for (int p = 0; p < 4; ++p) {
        int r = p * 16 + (tid >> 4);         // k within tile
        int c = (tid & 15) * 4;              // n within tile
        f32x4 v = *(const f32x4*)(wl + (size_t)(k0 + r) * H_DIM + n0 + c);
        *(unsigned int*)&tile[r][c] = pack_fp8x4(v[0], v[1], v[2], v[3]);
    }
    __syncthreads();
    const int nl = tid >> 2;                 // n within tile
    const int g  = tid & 3;                  // 16B k-chunk within 64
    unsigned int words[4];
#pragma unroll
    for (int wi = 0; wi < 4; ++wi) {
        unsigned int a = 0;
#pragma unroll
        for (int b = 0; b < 4; ++b)
            a |= (unsigned int)tile[g * 16 + wi * 4 + b][nl] << (8 * b);
        words[wi] = a;
    }
    const int bn = n0 >> 8, wc = (n0 >> 6) & 3, kt = k0 >> 6;
    const int n2 = nl >> 5;
    const int lane = (g >> 1) * 32 + (nl & 31);
    const int byte0 = (g & 1) * 16;
    const size_t off = ((((size_t)l * 16 + bn) * 64 + kt) * 4 + wc) * 2 + n2;
    unsigned char* op = wqT + off * 2048 + lane * 32 + byte0;
    uint4 ov; ov.x = words[0]; ov.y = words[1]; ov.z = words[2]; ov.w = words[3];
    *(uint4*)op = ov;
}

// ---------------- row-wise RMSNorm (+relu) (+quant) ----------------
// MODE 0: x = relu(in); resid_out = x; qx = fp8 (plain layout)
// MODE 1: x = in;                      qx = fp8 (plain layout)
// MODE 2: x = in;                      out = f32 rms(x)*g
template <int MODE>
__global__ __launch_bounds__(256) void row_kernel(
    const float* __restrict__ in,
    float* __restrict__ resid_out,
    void* __restrict__ out,
    const float* __restrict__ g,
    const float* __restrict__ scale_p)
{
    const int row = blockIdx.x;
    const int tid = threadIdx.x;
    const float* rin = in + (size_t)row * H_DIM;
    float x[16];
    float ss = 0.0f;
#pragma unroll
    for (int j = 0; j < 4; ++j) {
        const int base = (j * 256 + tid) * 4;
        f32x4 v = *(const f32x4*)(rin + base);
        f32x4 rv;
#pragma unroll
        for (int i = 0; i < 4; ++i) {
            float t = v[i];
            if (MODE == 0) t = fmaxf(t, 0.0f);
            x[j * 4 + i] = t;
            rv[i] = t;
            ss += t * t;
        }
        if (MODE == 0)
            *(f32x4*)(resid_out + (size_t)row * H_DIM + base) = rv;
    }
#pragma unroll
    for (int off = 32; off > 0; off >>= 1)
        ss += __shfl_down(ss, off, 64);
    __shared__ float red[4];
    if ((tid & 63) == 0) red[tid >> 6] = ss;
    __syncthreads();
    const float var  = (red[0] + red[1] + red[2] + red[3]) * (1.0f / (float)H_DIM);
    const float rinv = 1.0f / sqrtf(var + 1e-6f);

    if (MODE == 2) {
        float* ro = (float*)out + (size_t)row * H_DIM;
#pragma unroll
        for (int j = 0; j < 4; ++j) {
            const int base = (j * 256 + tid) * 4;
            f32x4 gv = *(const f32x4*)(g + base);
            f32x4 ov;
#pragma unroll
            for (int i = 0; i < 4; ++i) ov[i] = (x[j * 4 + i] * rinv) * gv[i];
            *(f32x4*)(ro + base) = ov;
        }
    } else {
        const float s = scale_p[0];
        unsigned int* qo = (unsigned int*)out + (size_t)row * (H_DIM / 4);
#pragma unroll
        for (int j = 0; j < 4; ++j) {
            const int base = (j * 256 + tid) * 4;
            f32x4 gv = *(const f32x4*)(g + base);
            float q[4];
#pragma unroll
            for (int i = 0; i < 4; ++i) {
                float y = (x[j * 4 + i] * rinv) * gv[i];
                y = y / s;
                q[i] = fminf(fmaxf(y, -448.0f), 448.0f);
            }
            qo[j * 256 + tid] = pack_fp8x4(q[0], q[1], q[2], q[3]);
        }
    }
}

// ---- MX-fp8 GEMM, 256x256 tile, BK=64: 2 tiles per sync period ----
__device__ __forceinline__ void stage_half(const unsigned char* gsrc, unsigned char* ldsdst) {
    __builtin_amdgcn_global_load_lds(
        (const __attribute__((address_space(1))) unsigned int*)gsrc,
        (__attribute__((address_space(3))) unsigned int*)ldsdst, 16, 0, 0);
}

#define VM8 asm volatile("s_waitcnt vmcnt(8)" ::: "memory")
#define VM4 asm volatile("s_waitcnt vmcnt(4)" ::: "memory")
#define VM0 asm volatile("s_waitcnt vmcnt(0)" ::: "memory")
#define BAR __builtin_amdgcn_s_barrier()
#define PRIO1 __builtin_amdgcn_s_setprio(1)
#define PRIO0 __builtin_amdgcn_s_setprio(0)

#define MM2(m, S) do {                                                          \
    acc[m][0] = __builtin_amdgcn_mfma_scale_f32_32x32x64_f8f6f4(                \
        fa[m], b##S##0, acc[m][0], 0, 0, 0, SC1, 0, SC1);                       \
    acc[m][1] = __builtin_amdgcn_mfma_scale_f32_32x32x64_f8f6f4(                \
        fa[m], b##S##1, acc[m][1], 0, 0, 0, SC1, 0, SC1);                       \
} while (0)

#define RDA(BUF, m) do {                                                        \
    *(i32x4*)&fa[m]         = *(const i32x4*)(lds + (BUF) + wrA + (m) * 2048 + fo0); \
    *(((i32x4*)&fa[m]) + 1) = *(const i32x4*)(lds + (BUF) + wrA + (m) * 2048 + fo1); \
} while (0)

// compute one tile with B-set S (frags in fa), read next tile's frags from BR
#define TILEBODY(S, BR) do {                                                    \
    PRIO1; MM2(0, S); PRIO0; RDA(BR, 0);                                        \
    PRIO1; MM2(1, S); PRIO0; RDA(BR, 1);                                        \
    PRIO1; MM2(2, S); PRIO0; RDA(BR, 2);                                        \
    PRIO1; MM2(3, S); PRIO0; RDA(BR, 3);                                        \
    __builtin_amdgcn_sched_group_barrier(0x008, 4, 0);                          \
    __builtin_amdgcn_sched_group_barrier(0x100, 4, 0);                          \
    __builtin_amdgcn_sched_group_barrier(0x008, 4, 0);                          \
    __builtin_amdgcn_sched_group_barrier(0x100, 4, 0);                          \
} while (0)

#define TILELAST(S) do {                                                        \
    PRIO1; MM2(0, S); MM2(1, S); MM2(2, S); MM2(3, S); PRIO0;                   \
} while (0)

#define LDB(NX) do {                                                            \
    bE##NX##0 = *(const i32x8*)(gB0 + kb);                                      \
    bE##NX##1 = *(const i32x8*)(gB0 + kb + 2048);                               \
    bO##NX##0 = *(const i32x8*)(gB0 + kb + 16384);                              \
    bO##NX##1 = *(const i32x8*)(gB0 + kb + 16384 + 2048);                       \
    kb += 32768;                                                                \
} while (0)

#define STG(KOFF, BUF) do {                                                     \
    stage_half(gAlo + (KOFF), lds + (BUF) + wave * 1024);                       \
    stage_half(gAhi + (KOFF), lds + (BUF) + 8192 + wave * 1024);                \
} while (0)

// period u (tiles 2u, 2u+1): load B(2u+2),B(2u+3)->NX sets; stage A(2u+4),
// A(2u+5); VM8 drains prior period's 8 ops; barrier; compute both tiles,
// reading frags of tiles 2u+1 (BR1) and 2u+2 (BR2).
#define ITER(CU, NX, BR1, BR2, BS1, BS2) do {                                   \
    LDB(NX);                                                                    \
    STG(ka, BS1); STG(ka + 64, BS2); ka += 128;                                 \
    VM8; BAR;                                                                   \
    TILEBODY(E##CU, BR1);                                                       \
    TILEBODY(O##CU, BR2);                                                       \
} while (0)

__global__ __launch_bounds__(512, 2) void gemm_fp8_kernel(
    const unsigned char* __restrict__ A,   // qx, plain row-major
    const unsigned char* __restrict__ B,   // wqT layer, frag-major
    float* __restrict__ C,
    const float* __restrict__ s_in,
    const float* __restrict__ s_w)
{
    __shared__ unsigned char lds[98304];   // 6 A-tile buffers x 16KB

    const float alpha = s_in[0] * s_w[0];

    // XCD-bijective swizzle (512 blocks = 64/XCD) + 8x8 supertile per XCD
    const int b = blockIdx.x;
    const int local = b >> 3, chunk = b & 7;         // chunk = XCD id
    const int bm = (chunk & 3) * 8 + (local & 7);    // M/256 = 32
    const int bn = (chunk >> 2) * 8 + (local >> 3);  // N/256 = 16

    const int tid  = threadIdx.x;
    const int wave = tid >> 6;
    const int lane = tid & 63;
    const int wr   = wave >> 2;   // 2 M-waves
    const int wc   = wave & 3;    // 4 N-waves

    // A frag ds_read: row=(lane&31), slot=(lane>>5)*2+h, stored^((row>>1)&3)
    const int sw  = (lane >> 1) & 3;
    const int fo0 = (lane & 31) * 64 + ((((lane >> 5) * 2) + 0 ^ sw)) * 16;
    const int fo1 = (lane & 31) * 64 + ((((lane >> 5) * 2) + 1 ^ sw)) * 16;
    const int wrA = wr * 8192;            // A region: 128 rows per wr

    // A staging: thread tid covers LDS [row=tid>>2][slot=tid&3]; global XOR'd
    const int voff = (tid >> 2) * H_DIM + ((tid & 3) ^ ((tid >> 3) & 3)) * 16;
    const unsigned char* gAlo = A + (size_t)bm * 256 * H_DIM + voff;
    const unsigned char* gAhi = gAlo + (size_t)128 * H_DIM;

    // B frag-major: base for (bn, kt=0, wc, n2=0) + lane*32; coalesced 2KB/wave
    const unsigned char* gB0 =
        B + ((((size_t)bn * 64) * 4 + wc) * 2) * 2048 + lane * 32;

    f32x16 acc[4][2];
#pragma unroll
    for (int m = 0; m < 4; ++m)
#pragma unroll
        for (int n = 0; n < 2; ++n)
#pragma unroll
            for (int e = 0; e < 16; ++e) acc[m][n][e] = 0.0f;

    i32x8 fa[4];
    i32x8 bEA0, bEA1, bOA0, bOA1, bEB0, bEB1, bOB0, bOB1;
    int ka, kb;

    // prologue: A tiles 0..3 -> bufs 0..3; B0->EA, B1->OA; drain; frags tile0
    STG(0,   0);
    STG(64,  16384);
    STG(128, 32768);
    STG(192, 49152);
    kb = 0; LDB(A);          // B0,B1; kb -> 32768 (tile 2)
    VM0; BAR;
    RDA(0, 0); RDA(0, 1); RDA(0, 2); RDA(0, 3);
    ka = 256;                // next A stage: tile 4

    // periods 0..29 (tiles 0..59): pattern period 6 (B parity 2 x buf cycle 3)
#pragma unroll 1
    for (int it = 0; it < 5; ++it) {
        ITER(A, B, 16384, 32768, 65536, 81920);   // u%6=0
        ITER(B, A, 49152, 65536, 0,     16384);   // u%6=1
        ITER(A, B, 81920, 0,     32768, 49152);   // u%6=2
        ITER(B, A, 16384, 32768, 65536, 81920);   // u%6=3
        ITER(A, B, 49152, 65536, 0,     16384);   // u%6=4
        ITER(B, A, 81920, 0,     32768, 49152);   // u%6=5
    }
    // period 30 (tiles 60,61): load B62,B63->EB/OB; no stage; drain A62,A63
    LDB(B);
    VM4; BAR;
    TILEBODY(EA, 16384);     // tile 60; RDA tile 61 (buf 1)
    TILEBODY(OA, 32768);     // tile 61; RDA tile 62 (buf 2)
    // period 31 (tiles 62,63)
    VM0; BAR;
    TILEBODY(EB, 49152);     // tile 62; RDA tile 63 (buf 3)
    TILELAST(OB);            // tile 63

    // epilogue: C += acc*alpha
    // (32x32 C/D: col = lane&31, row = (e&3) + 8*(e>>2) + 4*(lane>>5))
    const int lrow0 = bm * 256 + wr * 128 + 4 * (lane >> 5);
    const int lcol0 = bn * 256 + wc * 64 + (lane & 31);
#pragma unroll
    for (int m = 0; m < 4; ++m) {
#pragma unroll
        for (int n = 0; n < 2; ++n) {
#pragma unroll
            for (int e = 0; e < 16; ++e) {
                const int row = lrow0 + m * 32 + (e & 3) + 8 * (e >> 2);
                float* cp = C + (size_t)row * H_DIM + lcol0 + n * 32;
                *cp = acc[m][n][e] * alpha + *cp;
            }
        }
    }
}

extern "C" void kernel_launch(void* const* d_in, const int* in_sizes, int n_in,
                              void* d_out, int out_size, void* d_ws, size_t ws_size,
                              hipStream_t stream) {
    const float* h   = (const float*)d_in[0];   // [8192,4096]
    const float* nw  = (const float*)d_in[1];   // [4,4096]
    const float* w   = (const float*)d_in[2];   // [3,4096,4096]
    const float* wsc = (const float*)d_in[3];   // [3]
    const float* sc  = (const float*)d_in[4];   // [3]
    float* out = (float*)d_out;

    unsigned char* wqT = (unsigned char*)d_ws;                       // 3*16M fp8
    unsigned char* qx  = wqT + (size_t)3 * H_DIM * H_DIM;            // 33.5M fp8
    float* resid = (float*)(qx + (size_t)T_DIM * H_DIM);             // 134M f32

    const size_t WSTRIDE = (size_t)H_DIM * H_DIM;

    wquant_kernel<<<dim3(64, 64, 3), 256, 0, stream>>>(w, wqT);

    row_kernel<0><<<T_DIM, 256, 0, stream>>>(h, resid, qx, nw + 0 * H_DIM, sc + 0);
    gemm_fp8_kernel<<<512, 512, 0, stream>>>(qx, wqT + 0 * WSTRIDE, resid, sc + 0, wsc + 0);

    row_kernel<1><<<T_DIM, 256, 0, stream>>>(resid, nullptr, qx, nw + 1 * H_DIM, sc + 1);
    gemm_fp8_kernel<<<512, 512, 0, stream>>>(qx, wqT + 1 * WSTRIDE, resid, sc + 1, wsc + 1);

    row_kernel<1><<<T_DIM, 256, 0, stream>>>(resid, nullptr, qx, nw + 2 * H_DIM, sc + 2);
    gemm_fp8_kernel<<<512, 512, 0, stream>>>(qx, wqT + 2 * WSTRIDE, resid, sc + 2, wsc + 2);

    row_kernel<2><<<T_DIM, 256, 0, stream>>>(resid, nullptr, out, nw + 3 * H_DIM, nullptr);
}

// Round 14
// 712.748 us; speedup vs baseline: 1.6226x; 1.0591x over previous
//
#include <hip/hip_runtime.h>

typedef float f32x4  __attribute__((ext_vector_type(4)));
typedef float f32x16 __attribute__((ext_vector_type(16)));
typedef int   i32x4  __attribute__((ext_vector_type(4)));
typedef int   i32x8  __attribute__((ext_vector_type(8)));

#define T_DIM 8192
#define H_DIM 4096
#define SC1 0x7f7f7f7f   // e8m0 scale = 127 -> 2^0 = 1.0 in all 4 bytes

__device__ __forceinline__ unsigned int pack_fp8x4(float a, float b, float c, float d) {
    int v = __builtin_amdgcn_cvt_pk_fp8_f32(a, b, 0, false);
    v = __builtin_amdgcn_cvt_pk_fp8_f32(c, d, v, true);
    return (unsigned int)v;
}

// ---------------------------------------------------------------------------
// qx (A): PLAIN row-major [row][k]; staged via global_load_lds with XOR slot
//   swizzle slot' = slot ^ ((row>>1)&3) applied on the GLOBAL source address
//   (LDS image linear); ds_read applies the same XOR -> bank-balanced b128.
// wqT (B): FRAG-MAJOR (256-col-panel units):
//   addr = ((((l*16+bn256)*64+kt)*4+wc')*2+n2)*2048 + lane*32 + byte.
// GEMM: 256x128 tile, 8 waves of 64x64 output (acc=64 VGPR) -> <=128 regs
//   -> 2 blocks/CU co-resident; 3-buf A LDS, 1 barrier/tile, counted VM6.
// ---------------------------------------------------------------------------

// w[l][k][n] f32  ->  wqT[l] frag-major fp8(e4m3)
__global__ __launch_bounds__(256) void wquant_kernel(
    const float* __restrict__ w, unsigned char* __restrict__ wqT)
{
    const int l  = blockIdx.z;
    const int n0 = blockIdx.x * 64;
    const int k0 = blockIdx.y * 64;
    const int tid = threadIdx.x;
    __shared__ unsigned char tile[64][68];   // [k][n]
    const float* wl = w + (size_t)l * H_DIM * H_DIM;
#pragma unroll
    for (int p = 0; p < 4; ++p) {
        int r = p * 16 + (tid >> 4);         // k within tile
        int c = (tid & 15) * 4;              // n within tile
        f32x4 v = *(const f32x4*)(wl + (size_t)(k0 + r) * H_DIM + n0 + c);
        *(unsigned int*)&tile[r][c] = pack_fp8x4(v[0], v[1], v[2], v[3]);
    }
    __syncthreads();
    const int nl = tid >> 2;                 // n within tile
    const int g  = tid & 3;                  // 16B k-chunk within 64
    unsigned int words[4];
#pragma unroll
    for (int wi = 0; wi < 4; ++wi) {
        unsigned int a = 0;
#pragma unroll
        for (int b = 0; b < 4; ++b)
            a |= (unsigned int)tile[g * 16 + wi * 4 + b][nl] << (8 * b);
        words[wi] = a;
    }
    const int bn = n0 >> 8, wc = (n0 >> 6) & 3, kt = k0 >> 6;
    const int n2 = nl >> 5;
    const int lane = (g >> 1) * 32 + (nl & 31);
    const int byte0 = (g & 1) * 16;
    const size_t off = ((((size_t)l * 16 + bn) * 64 + kt) * 4 + wc) * 2 + n2;
    unsigned char* op = wqT + off * 2048 + lane * 32 + byte0;
    uint4 ov; ov.x = words[0]; ov.y = words[1]; ov.z = words[2]; ov.w = words[3];
    *(uint4*)op = ov;
}

// ---------------- row-wise RMSNorm (+relu) (+quant) ----------------
template <int MODE>
__global__ __launch_bounds__(256) void row_kernel(
    const float* __restrict__ in,
    float* __restrict__ resid_out,
    void* __restrict__ out,
    const float* __restrict__ g,
    const float* __restrict__ scale_p)
{
    const int row = blockIdx.x;
    const int tid = threadIdx.x;
    const float* rin = in + (size_t)row * H_DIM;
    float x[16];
    float ss = 0.0f;
#pragma unroll
    for (int j = 0; j < 4; ++j) {
        const int base = (j * 256 + tid) * 4;
        f32x4 v = *(const f32x4*)(rin + base);
        f32x4 rv;
#pragma unroll
        for (int i = 0; i < 4; ++i) {
            float t = v[i];
            if (MODE == 0) t = fmaxf(t, 0.0f);
            x[j * 4 + i] = t;
            rv[i] = t;
            ss += t * t;
        }
        if (MODE == 0)
            *(f32x4*)(resid_out + (size_t)row * H_DIM + base) = rv;
    }
#pragma unroll
    for (int off = 32; off > 0; off >>= 1)
        ss += __shfl_down(ss, off, 64);
    __shared__ float red[4];
    if ((tid & 63) == 0) red[tid >> 6] = ss;
    __syncthreads();
    const float var  = (red[0] + red[1] + red[2] + red[3]) * (1.0f / (float)H_DIM);
    const float rinv = 1.0f / sqrtf(var + 1e-6f);

    if (MODE == 2) {
        float* ro = (float*)out + (size_t)row * H_DIM;
#pragma unroll
        for (int j = 0; j < 4; ++j) {
            const int base = (j * 256 + tid) * 4;
            f32x4 gv = *(const f32x4*)(g + base);
            f32x4 ov;
#pragma unroll
            for (int i = 0; i < 4; ++i) ov[i] = (x[j * 4 + i] * rinv) * gv[i];
            *(f32x4*)(ro + base) = ov;
        }
    } else {
        const float s = scale_p[0];
        unsigned int* qo = (unsigned int*)out + (size_t)row * (H_DIM / 4);
#pragma unroll
        for (int j = 0; j < 4; ++j) {
            const int base = (j * 256 + tid) * 4;
            f32x4 gv = *(const f32x4*)(g + base);
            float q[4];
#pragma unroll
            for (int i = 0; i < 4; ++i) {
                float y = (x[j * 4 + i] * rinv) * gv[i];
                y = y / s;
                q[i] = fminf(fmaxf(y, -448.0f), 448.0f);
            }
            qo[j * 256 + tid] = pack_fp8x4(q[0], q[1], q[2], q[3]);
        }
    }
}

// ---- MX-fp8 GEMM, 256x128 tile, 64x64 waves, 2 blocks/CU, 3-buf A LDS ----
__device__ __forceinline__ void stage_half(const unsigned char* gsrc, unsigned char* ldsdst) {
    __builtin_amdgcn_global_load_lds(
        (const __attribute__((address_space(1))) unsigned int*)gsrc,
        (__attribute__((address_space(3))) unsigned int*)ldsdst, 16, 0, 0);
}

#define BUFA 0
#define BUFB 16384
#define BUFC 32768
#define VM6 asm volatile("s_waitcnt vmcnt(6)" ::: "memory")
#define VM4 asm volatile("s_waitcnt vmcnt(4)" ::: "memory")
#define LGKM0 asm volatile("s_waitcnt lgkmcnt(0)" ::: "memory")
#define BAR __builtin_amdgcn_s_barrier()
#define PRIO1 __builtin_amdgcn_s_setprio(1)
#define PRIO0 __builtin_amdgcn_s_setprio(0)

#define MM4(P) do {                                                             \
    acc[0][0] = __builtin_amdgcn_mfma_scale_f32_32x32x64_f8f6f4(                \
        fa[0], b##P##0, acc[0][0], 0, 0, 0, SC1, 0, SC1);                       \
    acc[0][1] = __builtin_amdgcn_mfma_scale_f32_32x32x64_f8f6f4(                \
        fa[0], b##P##1, acc[0][1], 0, 0, 0, SC1, 0, SC1);                       \
    acc[1][0] = __builtin_amdgcn_mfma_scale_f32_32x32x64_f8f6f4(                \
        fa[1], b##P##0, acc[1][0], 0, 0, 0, SC1, 0, SC1);                       \
    acc[1][1] = __builtin_amdgcn_mfma_scale_f32_32x32x64_f8f6f4(                \
        fa[1], b##P##1, acc[1][1], 0, 0, 0, SC1, 0, SC1);                       \
} while (0)

#define RDA(BUF, m) do {                                                        \
    *(i32x4*)&fa[m]         = *(const i32x4*)(lds + (BUF) + wrA + (m) * 2048 + fo0); \
    *(((i32x4*)&fa[m]) + 1) = *(const i32x4*)(lds + (BUF) + wrA + (m) * 2048 + fo1); \
} while (0)

#define STG(KOFF, BUF) do {                                                     \
    stage_half(gAlo + (KOFF), lds + (BUF) + wave * 1024);                       \
    stage_half(gAhi + (KOFF), lds + (BUF) + 8192 + wave * 1024);                \
} while (0)

// tile t: BAR; read A(t) frags from RB; stage A(t+2)->WB; load B(t+1)->FN;
// MFMA(t) with FC; lgkm0 (reads retired before RB's overwrite 2 tiles on);
// VM6 (A(t+1) landed before next BAR -> cross-wave safe).
#define ITER(RB, WB, FC, FN) do {                                               \
    BAR;                                                                        \
    RDA(RB, 0); RDA(RB, 1);                                                     \
    STG(ka, WB); ka += 64;                                                      \
    b##FN##0 = *(const i32x8*)(gB0 + kb);                                       \
    b##FN##1 = *(const i32x8*)(gB0 + kb + 2048);                                \
    kb += 16384;                                                                \
    PRIO1; MM4(FC); PRIO0;                                                      \
    LGKM0; VM6;                                                                 \
} while (0)

__global__ __launch_bounds__(512, 4) void gemm_fp8_kernel(
    const unsigned char* __restrict__ A,   // qx, plain row-major
    const unsigned char* __restrict__ B,   // wqT layer, frag-major
    float* __restrict__ C,
    const float* __restrict__ s_in,
    const float* __restrict__ s_w)
{
    __shared__ unsigned char lds[49152];   // 3 A-tile buffers x 16KB

    const float alpha = s_in[0] * s_w[0];

    // 1024 blocks: XCD chunk of 128; same-bm blocks share an XCD (A in L2)
    const int b = blockIdx.x;
    const int chunk = b & 7, local = b >> 3;
    const int bm = chunk * 4 + (local >> 5);   // M/256 = 32
    const int bn = local & 31;                 // N/128 = 32

    const int tid  = threadIdx.x;
    const int wave = tid >> 6;
    const int lane = tid & 63;
    const int wr   = wave >> 1;   // 4 M-waves (64 rows each)
    const int wc   = wave & 1;    // 2 N-waves (64 cols each)

    // A frag ds_read: row=(lane&31), slot=(lane>>5)*2+h, stored^((row>>1)&3)
    const int sw  = (lane >> 1) & 3;
    const int fo0 = (lane & 31) * 64 + ((((lane >> 5) * 2) + 0 ^ sw)) * 16;
    const int fo1 = (lane & 31) * 64 + ((((lane >> 5) * 2) + 1 ^ sw)) * 16;
    const int wrA = wr * 4096;            // A region: 64 rows per wr

    // A staging: thread tid covers LDS [row=tid>>2][slot=tid&3]; global XOR'd
    const int voff = (tid >> 2) * H_DIM + ((tid & 3) ^ ((tid >> 3) & 3)) * 16;
    const unsigned char* gAlo = A + (size_t)bm * 256 * H_DIM + voff;
    const unsigned char* gAhi = gAlo + (size_t)128 * H_DIM;

    // B frag-major: col-block-32 index cb = bn*4 + wc*2 (+n)
    const int cb = bn * 4 + wc * 2;
    const unsigned char* gB0 =
        B + ((((size_t)(cb >> 3) * 64) * 4 + ((cb >> 1) & 3)) * 2 + (cb & 1)) * 2048
          + lane * 32;

    f32x16 acc[2][2];
#pragma unroll
    for (int m = 0; m < 2; ++m)
#pragma unroll
        for (int n = 0; n < 2; ++n)
#pragma unroll
            for (int e = 0; e < 16; ++e) acc[m][n][e] = 0.0f;

    i32x8 fa[2];
    i32x8 bE0, bE1, bO0, bO1;

    // prologue: A0->bufA, A1->bufB (4 VMEM); B0->E (4 VMEM); VM4 drains A0,A1
    STG(0,  BUFA);
    STG(64, BUFB);
    bE0 = *(const i32x8*)(gB0);
    bE1 = *(const i32x8*)(gB0 + 2048);
    VM4;
    int ka = 128;     // next A stage: tile 2
    int kb = 16384;   // next B load: tile 1

    // t = 0..59: pattern period 6 (buf cycle 3 x fb parity 2)
#pragma unroll 1
    for (int it = 0; it < 10; ++it) {
        ITER(BUFA, BUFC, E, O);   // t%6=0
        ITER(BUFB, BUFA, O, E);   // t%6=1
        ITER(BUFC, BUFB, E, O);   // t%6=2
        ITER(BUFA, BUFC, O, E);   // t%6=3
        ITER(BUFB, BUFA, E, O);   // t%6=4
        ITER(BUFC, BUFB, O, E);   // t%6=5
    }
    ITER(BUFA, BUFC, E, O);       // t=60 (stages A62, loads B61)
    ITER(BUFB, BUFA, O, E);       // t=61 (stages A63, loads B62)
    // t = 62: no stage; load B63->O; compute E; VM4 -> A63 landed
    BAR;
    RDA(BUFC, 0); RDA(BUFC, 1);
    bO0 = *(const i32x8*)(gB0 + kb);
    bO1 = *(const i32x8*)(gB0 + kb + 2048);
    PRIO1; MM4(E); PRIO0;
    LGKM0; VM4;
    // t = 63
    BAR;
    RDA(BUFA, 0); RDA(BUFA, 1);
    PRIO1; MM4(O); PRIO0;

    // epilogue: C += acc*alpha
    // (32x32 C/D: col = lane&31, row = (e&3) + 8*(e>>2) + 4*(lane>>5))
    const int lrow0 = bm * 256 + wr * 64 + 4 * (lane >> 5);
    const int lcol0 = bn * 128 + wc * 64 + (lane & 31);
#pragma unroll
    for (int m = 0; m < 2; ++m) {
#pragma unroll
        for (int n = 0; n < 2; ++n) {
#pragma unroll
            for (int e = 0; e < 16; ++e) {
                const int row = lrow0 + m * 32 + (e & 3) + 8 * (e >> 2);
                float* cp = C + (size_t)row * H_DIM + lcol0 + n * 32;
                *cp = acc[m][n][e] * alpha + *cp;
            }
        }
    }
}

extern "C" void kernel_launch(void* const* d_in, const int* in_sizes, int n_in,
                              void* d_out, int out_size, void* d_ws, size_t ws_size,
                              hipStream_t stream) {
    const float* h   = (const float*)d_in[0];   // [8192,4096]
    const float* nw  = (const float*)d_in[1];   // [4,4096]
    const float* w   = (const float*)d_in[2];   // [3,4096,4096]
    const float* wsc = (const float*)d_in[3];   // [3]
    const float* sc  = (const float*)d_in[4];   // [3]
    float* out = (float*)d_out;

    unsigned char* wqT = (unsigned char*)d_ws;                       // 3*16M fp8
    unsigned char* qx  = wqT + (size_t)3 * H_DIM * H_DIM;            // 33.5M fp8
    float* resid = (float*)(qx + (size_t)T_DIM * H_DIM);             // 134M f32

    const size_t WSTRIDE = (size_t)H_DIM * H_DIM;

    wquant_kernel<<<dim3(64, 64, 3), 256, 0, stream>>>(w, wqT);

    row_kernel<0><<<T_DIM, 256, 0, stream>>>(h, resid, qx, nw + 0 * H_DIM, sc + 0);
    gemm_fp8_kernel<<<1024, 512, 0, stream>>>(qx, wqT + 0 * WSTRIDE, resid, sc + 0, wsc + 0);

    row_kernel<1><<<T_DIM, 256, 0, stream>>>(resid, nullptr, qx, nw + 1 * H_DIM, sc + 1);
    gemm_fp8_kernel<<<1024, 512, 0, stream>>>(qx, wqT + 1 * WSTRIDE, resid, sc + 1, wsc + 1);

    row_kernel<1><<<T_DIM, 256, 0, stream>>>(resid, nullptr, qx, nw + 2 * H_DIM, sc + 2);
    gemm_fp8_kernel<<<1024, 512, 0, stream>>>(qx, wqT + 2 * WSTRIDE, resid, sc + 2, wsc + 2);

    row_kernel<2><<<T_DIM, 256, 0, stream>>>(resid, nullptr, out, nw + 3 * H_DIM, nullptr);
}